// Round 5
// baseline (2966.858 us; speedup 1.0000x reference)
//
#include <hip/hip_runtime.h>
#include <math.h>

#define B_ 8
#define C_ 512
#define N_ 2048
#define M_ 2048
#define KSEL 614          /* int(2048*0.3) */
#define EPS_ 1e-5f

#define O_CORR 0
#define O_W    (B_*3*N_)          /* 49152 */
#define O_MSRC (O_W + B_*N_)      /* 65536 */
#define O_MTGT (O_MSRC + B_*N_)   /* 81920 */
#define O_ROT  (O_MTGT + B_*M_)   /* 98304 */
#define O_TR   (O_ROT + B_*9)     /* 98376 */

/* ---- fixed-order block tree reductions (256 threads) ---- */
__device__ inline float blk_sum(float v, float* sh){
  int t = threadIdx.x;
  sh[t] = v; __syncthreads();
  for (int s = 128; s > 0; s >>= 1) { if (t < s) sh[t] += sh[t+s]; __syncthreads(); }
  float r = sh[0]; __syncthreads(); return r;
}
__device__ inline float blk_max(float v, float* sh){
  int t = threadIdx.x;
  sh[t] = v; __syncthreads();
  for (int s = 128; s > 0; s >>= 1) { if (t < s) sh[t] = fmaxf(sh[t], sh[t+s]); __syncthreads(); }
  float r = sh[0]; __syncthreads(); return r;
}
__device__ inline double blk_sumd(double v, double* sh){
  int t = threadIdx.x;
  sh[t] = v; __syncthreads();
  for (int s = 128; s > 0; s >>= 1) { if (t < s) sh[t] += sh[t+s]; __syncthreads(); }
  double r = sh[0]; __syncthreads(); return r;
}

/* ---- xx / yy: per-column sum of squares over C ---- */
__global__ __launch_bounds__(256) void ksq(const float* __restrict__ X,
                                           float* __restrict__ out)
{
  int col = blockIdx.x*256 + threadIdx.x;
  int b = blockIdx.y;
  const float* base = X + (size_t)b*C_*N_;
  float s = 0.f;
  for (int c = 0; c < C_; ++c) { float v = base[(size_t)c*N_ + col]; s += v*v; }
  out[b*N_ + col] = s;
}

/* ---- GEMM: P = 2*A^T B - xx - yy  (f32, 64x64 tile, 4x4/thread) ---- */
__global__ __launch_bounds__(256) void kgemm(
    const float* __restrict__ Aemb, const float* __restrict__ Bemb,
    const float* __restrict__ xx, const float* __restrict__ yy,
    float* __restrict__ P, int b_off)
{
  int bn = blockIdx.x, bm = blockIdx.y, bz = blockIdx.z;
  int b = b_off + bz;
  const float* Ab = Aemb + (size_t)b*C_*N_ + bn*64;
  const float* Bb = Bemb + (size_t)b*C_*M_ + bm*64;
  __shared__ float As[16][64];
  __shared__ float Bs[16][64];
  int tid = threadIdx.x;
  int ty = tid >> 4, tx = tid & 15;
  float acc[4][4] = {{0.f}};
  for (int k0 = 0; k0 < C_; k0 += 16) {
#pragma unroll
    for (int j = 0; j < 4; ++j) {
      int idx = tid + 256*j;
      int kk = idx >> 6, nl = idx & 63;
      As[kk][nl] = Ab[(size_t)(k0+kk)*N_ + nl];
      Bs[kk][nl] = Bb[(size_t)(k0+kk)*M_ + nl];
    }
    __syncthreads();
#pragma unroll
    for (int kk = 0; kk < 16; ++kk) {
      float av[4], bv[4];
#pragma unroll
      for (int i = 0; i < 4; ++i) av[i] = As[kk][ty*4+i];
#pragma unroll
      for (int j = 0; j < 4; ++j) bv[j] = Bs[kk][tx*4+j];
#pragma unroll
      for (int i = 0; i < 4; ++i)
#pragma unroll
        for (int j = 0; j < 4; ++j) acc[i][j] += av[i]*bv[j];
    }
    __syncthreads();
  }
  int n0 = bn*64 + ty*4, m0 = bm*64 + tx*4;
  float xv[4], yv[4];
#pragma unroll
  for (int i = 0; i < 4; ++i) xv[i] = xx[b*N_ + n0 + i];
#pragma unroll
  for (int j = 0; j < 4; ++j) yv[j] = yy[b*M_ + m0 + j];
  float* Pb = P + (size_t)bz*N_*M_;
#pragma unroll
  for (int i = 0; i < 4; ++i) {
    float4 o;
    o.x = 2.f*acc[i][0] - xv[i] - yv[0];
    o.y = 2.f*acc[i][1] - xv[i] - yv[1];
    o.z = 2.f*acc[i][2] - xv[i] - yv[2];
    o.w = 2.f*acc[i][3] - xv[i] - yv[3];
    *(float4*)(Pb + (size_t)(n0+i)*M_ + m0) = o;
  }
}

/* ---- row softmax: SSC = exp(P - rowmax)/Z, rmaxS = max of stored SSC ---- */
__global__ __launch_bounds__(256) void krowstat(const float* __restrict__ P,
                                                float* __restrict__ SSC,
                                                float* __restrict__ rmaxS, int b_off)
{
  __shared__ float rowc[M_];
  __shared__ float shf[256];
  __shared__ double shd[256];
  int r = blockIdx.x, t = threadIdx.x;
  const float* prow = P + (size_t)r*M_;
  float* srow = SSC + (size_t)r*M_;
  float mx = -3.4e38f;
  for (int m = t; m < M_; m += 256) { float v = prow[m]; rowc[m] = v; mx = fmaxf(mx, v); }
  mx = blk_max(mx, shf);
  double z = 0.0;
  for (int m = t; m < M_; m += 256) z += (double)expf(rowc[m] - mx);
  z = blk_sumd(z, shd);
  float zf = (float)z;
  float smx = 0.f;
  for (int m = t; m < M_; m += 256) {
    float sv = expf(rowc[m] - mx) / zf;
    srow[m] = sv;
    smx = fmaxf(smx, sv);
  }
  smx = blk_max(smx, shf);
  if (!t) { int b = b_off + r/N_, n = r%N_; rmaxS[b*N_+n] = smx; }
}

/* ---- column softmax stats of P: cpm = colmax, cZ = sum exp(P-cpm) ---- */
__global__ __launch_bounds__(256) void kcolstat(const float* __restrict__ P,
                                                float* __restrict__ cpm,
                                                float* __restrict__ cZ, int b_off)
{
  int col = blockIdx.x*256 + threadIdx.x;
  int bz = blockIdx.y;
  const float* base = P + (size_t)bz*N_*M_;
  float mx = -3.4e38f;
  for (int n = 0; n < N_; ++n) mx = fmaxf(mx, base[(size_t)n*M_ + col]);
  double z = 0.0;
  for (int n = 0; n < N_; ++n) z += (double)expf(base[(size_t)n*M_ + col] - mx);
  int b = b_off + bz;
  cpm[b*M_ + col] = mx;
  cZ[b*M_ + col] = (float)z;
}

/* ---- row_sum = sum_m exp(P-cpm[m])/cZ[m]  (f64) ---- */
__global__ __launch_bounds__(256) void krowsum2(const float* __restrict__ P,
                                                const float* __restrict__ cpm,
                                                const float* __restrict__ cZ,
                                                double* __restrict__ row_sum, int b_off)
{
  __shared__ double shd[256];
  int r = blockIdx.x, t = threadIdx.x;
  int b = b_off + r/N_, n = r%N_;
  const float* prow = P + (size_t)r*M_;
  const float* pm = cpm + b*M_;
  const float* pz = cZ + b*M_;
  double s = 0.0;
  for (int m = t; m < M_; m += 256) s += (double)(expf(prow[m] - pm[m]) / pz[m]);
  s = blk_sumd(s, shd);
  if (!t) row_sum[b*N_+n] = s;
}

/* ---- col_sum = sum_n SSC[n,m]  (f64) ---- */
__global__ __launch_bounds__(256) void kcolsum(const float* __restrict__ SSC,
                                               double* __restrict__ col_sum, int b_off)
{
  int col = blockIdx.x*256 + threadIdx.x;
  int bz = blockIdx.y;
  const float* base = SSC + (size_t)bz*N_*M_;
  double s = 0.0;
  for (int n = 0; n < N_; ++n) s += (double)base[(size_t)n*M_ + col];
  col_sum[(b_off+bz)*M_ + col] = s;
}

/* ---- exact K-th smallest via rank count ---- */
__global__ __launch_bounds__(256) void kkth(const double* __restrict__ vals,
                                            double* __restrict__ kth, int b_off)
{
  __shared__ double sv[2048];
  int b = b_off + blockIdx.x;
  const double* v = vals + b*2048;
  for (int i = threadIdx.x; i < 2048; i += 256) sv[i] = v[i];
  __syncthreads();
  for (int i = threadIdx.x; i < 2048; i += 256) {
    double vi = sv[i];
    int lt = 0, le = 0;
    for (int j = 0; j < 2048; ++j) {
      double vj = sv[j];
      lt += (vj < vi);
      le += (vj <= vi);
    }
    if (lt < KSEL && KSEL <= le) kth[b] = vi;
  }
}

/* ---- masks (float 0/1 outputs) ---- */
__global__ __launch_bounds__(256) void kmask(const double* __restrict__ vals,
                                             const double* __restrict__ kth,
                                             unsigned char* __restrict__ m8,
                                             float* __restrict__ mout,
                                             int b_off, int cur)
{
  int i = blockIdx.x*256 + threadIdx.x;
  if (i >= cur*2048) return;
  int b = b_off + i/2048, j = i & 2047;
  bool m = vals[b*2048 + j] < kth[b];
  m8[b*2048 + j] = m ? 1 : 0;
  mout[b*2048 + j] = m ? 1.f : 0.f;
}

/* ---- sparse renorm + vsi + src_corr (block per row) ---- */
__global__ __launch_bounds__(256) void kwcorr(
    const float* __restrict__ SSC, const float* __restrict__ rmaxS,
    const unsigned char* __restrict__ rowmask, const unsigned char* __restrict__ colmask,
    const float* __restrict__ tgt, float* __restrict__ vsi,
    float* __restrict__ corrf, float* __restrict__ corr_out, int b_off)
{
  __shared__ float rowc[M_];
  __shared__ float shf[256];
  int r = blockIdx.x, t = threadIdx.x;
  int b = b_off + r/N_, n = r%N_;
  const float* srow = SSC + (size_t)r*M_;
  for (int m = t; m < M_; m += 256) rowc[m] = srow[m];
  __syncthreads();
  float rmax = rmaxS[b*N_+n];
  int rm = rowmask[b*N_+n];
  const unsigned char* cm = colmask + b*M_;
  float s = 0.f;
  for (int m = t; m < M_; m += 256) {
    float v = rowc[m];
    if (rm || cm[m] || (v >= rmax)) s += v;
  }
  s = blk_sum(s, shf);
  float d = (s < EPS_) ? EPS_ : s;
  const float* t0 = tgt + (size_t)b*3*M_;
  float vs = 0.f, a0 = 0.f, a1 = 0.f, a2 = 0.f;
  for (int m = t; m < M_; m += 256) {
    float v = rowc[m];
    bool keep = rm || cm[m] || (v >= rmax);
    float wv = keep ? v/d : 0.f;
    vs += wv;
    a0 += wv * t0[m];
    a1 += wv * t0[M_+m];
    a2 += wv * t0[2*M_+m];
  }
  vs = blk_sum(vs, shf);
  a0 = blk_sum(a0, shf); a1 = blk_sum(a1, shf); a2 = blk_sum(a2, shf);
  if (!t) {
    vsi[b*N_+n] = rm ? 0.f : vs;
    size_t o = (size_t)b*3*N_ + n;
    corrf[o] = a0; corrf[o+N_] = a1; corrf[o+2*N_] = a2;
    corr_out[o]      = a0;
    corr_out[o+N_]   = a1;
    corr_out[o+2*N_] = a2;
  }
}

__global__ __launch_bounds__(256) void ksumvsi(const float* __restrict__ vsi,
                                               float* __restrict__ out)
{
  __shared__ double shd[256];
  int b = blockIdx.x;
  double s = 0.0;
  for (int n = threadIdx.x; n < N_; n += 256) s += (double)vsi[b*N_+n];
  s = blk_sumd(s, shd);
  if (!threadIdx.x) out[b] = (float)s;
}

__global__ __launch_bounds__(256) void kweights(const float* __restrict__ vsi,
                                                const float* __restrict__ sumvsi,
                                                float* __restrict__ srcw,
                                                float* __restrict__ wout)
{
  int i = blockIdx.x*256 + threadIdx.x;
  if (i >= B_*N_) return;
  int b = i / N_;
  float w = vsi[i] / sumvsi[b];
  srcw[i] = w;
  wout[i] = w;
}

__global__ __launch_bounds__(256) void kcov(const float* __restrict__ srcw,
                                            const float* __restrict__ src,
                                            const float* __restrict__ corrf,
                                            double* covd, double* cad, double* cbd)
{
  __shared__ double sh[256];
  int b = blockIdx.x, t = threadIdx.x;
  const float* w = srcw + b*N_;
  const float* a = src  + (size_t)b*3*N_;
  const float* bb = corrf + (size_t)b*3*N_;
  double sw = 0.0;
  for (int n = t; n < N_; n += 256) sw += (double)w[n];
  sw = blk_sumd(sw, sh);
  double inv = 1.0/(sw + 1e-5);
  double p0=0,p1=0,p2=0,p3=0,p4=0,p5=0;
  for (int n = t; n < N_; n += 256) {
    double wn = (double)w[n]*inv;
    p0 += (double)a[n]*wn;      p1 += (double)a[N_+n]*wn;   p2 += (double)a[2*N_+n]*wn;
    p3 += (double)bb[n]*wn;     p4 += (double)bb[N_+n]*wn;  p5 += (double)bb[2*N_+n]*wn;
  }
  double ca0 = blk_sumd(p0, sh), ca1 = blk_sumd(p1, sh), ca2 = blk_sumd(p2, sh);
  double cb0 = blk_sumd(p3, sh), cb1 = blk_sumd(p4, sh), cb2 = blk_sumd(p5, sh);
  double c[9] = {0,0,0,0,0,0,0,0,0};
  for (int n = t; n < N_; n += 256) {
    double wn = (double)w[n]*inv;
    double a0 = (double)a[n]-ca0, a1d = (double)a[N_+n]-ca1, a2d = (double)a[2*N_+n]-ca2;
    double b0 = ((double)bb[n]-cb0)*wn, b1 = ((double)bb[N_+n]-cb1)*wn, b2 = ((double)bb[2*N_+n]-cb2)*wn;
    c[0]+=a0*b0; c[1]+=a0*b1; c[2]+=a0*b2;
    c[3]+=a1d*b0; c[4]+=a1d*b1; c[5]+=a1d*b2;
    c[6]+=a2d*b0; c[7]+=a2d*b1; c[8]+=a2d*b2;
  }
  for (int k = 0; k < 9; ++k) {
    double rr = blk_sumd(c[k], sh);
    if (!t) covd[b*9+k] = rr;
  }
  if (!t) {
    cad[b*3+0]=ca0; cad[b*3+1]=ca1; cad[b*3+2]=ca2;
    cbd[b*3+0]=cb0; cbd[b*3+1]=cb1; cbd[b*3+2]=cb2;
  }
}

/* ---- 3x3 Kabsch via Jacobi eigendecomposition of H^T H (f64) ---- */
__global__ void ksvd(const double* __restrict__ covd, const double* __restrict__ cad,
                     const double* __restrict__ cbd, float* out)
{
  int b = threadIdx.x;
  if (b >= B_) return;
  double H[3][3];
  for (int i = 0; i < 3; ++i) for (int j = 0; j < 3; ++j) H[i][j] = covd[b*9+i*3+j];
  double A[3][3];
  for (int i = 0; i < 3; ++i)
    for (int j = 0; j < 3; ++j) {
      double s = 0.0;
      for (int l = 0; l < 3; ++l) s += H[l][i]*H[l][j];
      A[i][j] = s;
    }
  double V[3][3] = {{1,0,0},{0,1,0},{0,0,1}};
  const int PP[3] = {0,0,1}, QQ[3] = {1,2,2};
  for (int sweep = 0; sweep < 24; ++sweep) {
    double off = fabs(A[0][1])+fabs(A[0][2])+fabs(A[1][2]);
    if (off < 1e-28) break;
    for (int r = 0; r < 3; ++r) {
      int p = PP[r], q = QQ[r];
      double apq = A[p][q];
      if (fabs(apq) < 1e-300) continue;
      double th = (A[q][q]-A[p][p])/(2.0*apq);
      double tt = (th >= 0.0 ? 1.0 : -1.0)/(fabs(th)+sqrt(th*th+1.0));
      double cc = 1.0/sqrt(tt*tt+1.0), ss = tt*cc;
      for (int k = 0; k < 3; ++k) {
        double akp = A[k][p], akq = A[k][q];
        A[k][p] = cc*akp - ss*akq; A[k][q] = ss*akp + cc*akq;
      }
      for (int k = 0; k < 3; ++k) {
        double apk = A[p][k], aqk = A[q][k];
        A[p][k] = cc*apk - ss*aqk; A[q][k] = ss*apk + cc*aqk;
      }
      for (int k = 0; k < 3; ++k) {
        double vkp = V[k][p], vkq = V[k][q];
        V[k][p] = cc*vkp - ss*vkq; V[k][q] = ss*vkp + cc*vkq;
      }
    }
  }
  double lam[3] = {A[0][0], A[1][1], A[2][2]};
  int idx[3] = {0,1,2};
  for (int i = 0; i < 2; ++i)
    for (int j = i+1; j < 3; ++j)
      if (lam[idx[j]] > lam[idx[i]]) { int tmp = idx[i]; idx[i] = idx[j]; idx[j] = tmp; }
  double Vs[3][3], sig[3];
  for (int i = 0; i < 3; ++i) {
    for (int k = 0; k < 3; ++k) Vs[k][i] = V[k][idx[i]];
    double l = lam[idx[i]];
    sig[i] = sqrt(l > 0.0 ? l : 0.0);
  }
  double U[3][3];
  for (int i = 0; i < 3; ++i) {
    double inv = sig[i] > 1e-300 ? 1.0/sig[i] : 0.0;
    for (int k = 0; k < 3; ++k) {
      double u = H[k][0]*Vs[0][i] + H[k][1]*Vs[1][i] + H[k][2]*Vs[2][i];
      U[k][i] = u*inv;
    }
  }
  if (sig[2] <= 1e-9*sig[0]) {
    U[0][2] = U[1][0]*U[2][1] - U[2][0]*U[1][1];
    U[1][2] = U[2][0]*U[0][1] - U[0][0]*U[2][1];
    U[2][2] = U[0][0]*U[1][1] - U[1][0]*U[0][1];
  }
  double detH = H[0][0]*(H[1][1]*H[2][2]-H[1][2]*H[2][1])
              - H[0][1]*(H[1][0]*H[2][2]-H[1][2]*H[2][0])
              + H[0][2]*(H[1][0]*H[2][1]-H[1][1]*H[2][0]);
  double s3[3] = {1.0, 1.0, detH > 0.0 ? 1.0 : -1.0};
  double R[3][3];
  for (int d = 0; d < 3; ++d)
    for (int e = 0; e < 3; ++e) {
      double s = 0.0;
      for (int i = 0; i < 3; ++i) s += s3[i]*Vs[d][i]*U[e][i];
      R[d][e] = s;
    }
  double tr[3];
  for (int d = 0; d < 3; ++d)
    tr[d] = cbd[b*3+d] - (R[d][0]*cad[b*3+0] + R[d][1]*cad[b*3+1] + R[d][2]*cad[b*3+2]);
  for (int d = 0; d < 3; ++d)
    for (int e = 0; e < 3; ++e)
      out[O_ROT + b*9 + d*3 + e] = (float)R[d][e];
  for (int d = 0; d < 3; ++d)
    out[O_TR + b*3 + d] = (float)tr[d];
}

/* ---- canary: ws shortfall ---- */
__global__ void kfail(float* out, float v) { out[0] = v; }

/* ---- diagnostic canary (writes only if something is structurally wrong) ---- */
__global__ __launch_bounds__(256) void kdiag(const unsigned char* __restrict__ colmask,
                                             const unsigned char* __restrict__ rowmask,
                                             float* __restrict__ out)
{
  __shared__ float shf[256];
  __shared__ int cc[B_], rc[B_];
  int t = threadIdx.x;
  for (int b = 0; b < B_; ++b) {
    float c1 = 0.f, r1 = 0.f;
    for (int j = t; j < 2048; j += 256) { c1 += colmask[b*2048+j]; r1 += rowmask[b*2048+j]; }
    c1 = blk_sum(c1, shf); r1 = blk_sum(r1, shf);
    if (!t) { cc[b] = (int)(c1+0.5f); rc[b] = (int)(r1+0.5f); }
  }
  float mc = 0.f;
  for (int i = t; i < O_W; i += 256) mc = fmaxf(mc, fabsf(out[i]));
  mc = blk_max(mc, shf);
  __syncthreads();
  if (!t) {
    int A = 0, Bc = 0;
    for (int b = 0; b < B_; ++b) { A += (cc[b] == 613); Bc += (rc[b] == 613); }
    int hot = mc > 0.5f ? 1 : 0;
    if (A != B_ || Bc != B_ || hot) {
      int extra = (int)fminf(3.f, floorf(mc));
      int f = Bc*16 + hot*8 + extra;
      float enc = (1.f + (float)f/256.f) * (float)(1 << (6 + A));
      out[0] = enc;
    }
  }
}

extern "C" void kernel_launch(void* const* d_in, const int* in_sizes, int n_in,
                              void* d_out, int out_size, void* d_ws, size_t ws_size,
                              hipStream_t stream) {
  float* out = (float*)d_out;
  (void)out_size;

  /* input-order auto-detect: dict (src,tgt,src_emb,tgt_emb) vs alphabetical */
  int i_tgt = 1, i_semb = 2;
  if (n_in == 4 && in_sizes[1] == B_*C_*N_) { i_semb = 1; i_tgt = 2; }
  const float* src  = (const float*)d_in[0];
  const float* tgt  = (const float*)d_in[i_tgt];
  const float* semb = (const float*)d_in[i_semb];
  const float* temb = (const float*)d_in[3];

  char* w = (char*)d_ws;
  auto alloc = [&](size_t bytes) { char* p = w; w += (bytes + 255)/256*256; return p; };
  float*  xx      = (float*)alloc((size_t)B_*N_*4);
  float*  yy      = (float*)alloc((size_t)B_*M_*4);
  float*  rmaxS   = (float*)alloc((size_t)B_*N_*4);
  float*  cpm     = (float*)alloc((size_t)B_*M_*4);
  float*  cZ      = (float*)alloc((size_t)B_*M_*4);
  float*  vsi     = (float*)alloc((size_t)B_*N_*4);
  float*  srcw    = (float*)alloc((size_t)B_*N_*4);
  float*  sumvsi  = (float*)alloc((size_t)B_*4);
  float*  corrf   = (float*)alloc((size_t)B_*3*N_*4);
  double* col_sum = (double*)alloc((size_t)B_*M_*8);
  double* row_sum = (double*)alloc((size_t)B_*N_*8);
  double* kth_c   = (double*)alloc((size_t)B_*8);
  double* kth_r   = (double*)alloc((size_t)B_*8);
  unsigned char* rowmask = (unsigned char*)alloc((size_t)B_*N_);
  unsigned char* colmask = (unsigned char*)alloc((size_t)B_*M_);
  double* covd = (double*)alloc((size_t)B_*9*8);
  double* cad  = (double*)alloc((size_t)B_*3*8);
  double* cbd  = (double*)alloc((size_t)B_*3*8);

  size_t used = (size_t)(w - (char*)d_ws);
  size_t rem = ws_size > used ? ws_size - used : 0;
  size_t oneP = (size_t)N_*M_*sizeof(float);
  int bc = (int)(rem / (2*oneP));
  if (bc < 1) { kfail<<<1, 1, 0, stream>>>(out, 32768.f); return; }
  if (bc > B_) bc = B_;
  float* P = (float*)w;
  float* S = P + (size_t)bc*N_*M_;

  ksq<<<dim3(N_/256, B_), 256, 0, stream>>>(semb, xx);
  ksq<<<dim3(M_/256, B_), 256, 0, stream>>>(temb, yy);

  for (int b0 = 0; b0 < B_; b0 += bc) {
    int cur = (B_ - b0 < bc) ? (B_ - b0) : bc;
    kgemm   <<<dim3(N_/64, M_/64, cur), 256, 0, stream>>>(semb, temb, xx, yy, P, b0);
    krowstat<<<cur*N_, 256, 0, stream>>>(P, S, rmaxS, b0);
    kcolstat<<<dim3(M_/256, cur), 256, 0, stream>>>(P, cpm, cZ, b0);
    krowsum2<<<cur*N_, 256, 0, stream>>>(P, cpm, cZ, row_sum, b0);
    kcolsum <<<dim3(M_/256, cur), 256, 0, stream>>>(S, col_sum, b0);
    kkth<<<cur, 256, 0, stream>>>(col_sum, kth_c, b0);
    kkth<<<cur, 256, 0, stream>>>(row_sum, kth_r, b0);
    kmask<<<cur*8, 256, 0, stream>>>(col_sum, kth_c, colmask, out + O_MTGT, b0, cur);
    kmask<<<cur*8, 256, 0, stream>>>(row_sum, kth_r, rowmask, out + O_MSRC, b0, cur);
    kwcorr<<<cur*N_, 256, 0, stream>>>(S, rmaxS, rowmask, colmask, tgt,
                                       vsi, corrf, out + O_CORR, b0);
  }

  ksumvsi <<<B_, 256, 0, stream>>>(vsi, sumvsi);
  kweights<<<(B_*N_+255)/256, 256, 0, stream>>>(vsi, sumvsi, srcw, out + O_W);
  kcov    <<<B_, 256, 0, stream>>>(srcw, src, corrf, covd, cad, cbd);
  ksvd    <<<1, 64, 0, stream>>>(covd, cad, cbd, out);
  kdiag   <<<1, 256, 0, stream>>>(colmask, rowmask, out);
}

// Round 6
// 708.573 us; speedup vs baseline: 4.1871x; 4.1871x over previous
//
#include <hip/hip_runtime.h>
#include <math.h>

#define B_ 8
#define C_ 512
#define N_ 2048
#define M_ 2048
#define KSEL 614          /* int(2048*0.3) */
#define EPS_ 1e-5f
#define CS_ 8             /* c-chunks for ksq partials */
#define RS_ 16            /* row-chunks for column partials */

#define O_CORR 0
#define O_W    (B_*3*N_)          /* 49152 */
#define O_MSRC (O_W + B_*N_)      /* 65536 */
#define O_MTGT (O_MSRC + B_*N_)   /* 81920 */
#define O_ROT  (O_MTGT + B_*M_)   /* 98304 */
#define O_TR   (O_ROT + B_*9)     /* 98376 */

/* ---- fixed-order block tree reductions (256 threads) ---- */
__device__ inline float blk_sum(float v, float* sh){
  int t = threadIdx.x;
  sh[t] = v; __syncthreads();
  for (int s = 128; s > 0; s >>= 1) { if (t < s) sh[t] += sh[t+s]; __syncthreads(); }
  float r = sh[0]; __syncthreads(); return r;
}
__device__ inline float blk_max(float v, float* sh){
  int t = threadIdx.x;
  sh[t] = v; __syncthreads();
  for (int s = 128; s > 0; s >>= 1) { if (t < s) sh[t] = fmaxf(sh[t], sh[t+s]); __syncthreads(); }
  float r = sh[0]; __syncthreads(); return r;
}
__device__ inline double blk_sumd(double v, double* sh){
  int t = threadIdx.x;
  sh[t] = v; __syncthreads();
  for (int s = 128; s > 0; s >>= 1) { if (t < s) sh[t] += sh[t+s]; __syncthreads(); }
  double r = sh[0]; __syncthreads(); return r;
}

/* ---- xx/yy sum-of-squares: two-stage ---- */
__global__ __launch_bounds__(256) void ksqpart(const float* __restrict__ X,
                                               float* __restrict__ part)
{
  int col = blockIdx.x*256 + threadIdx.x;
  int cs = blockIdx.y, b = blockIdx.z;
  const float* base = X + (size_t)b*C_*N_;
  float s = 0.f;
  for (int c = cs*(C_/CS_); c < (cs+1)*(C_/CS_); ++c) {
    float v = base[(size_t)c*N_ + col]; s += v*v;
  }
  part[((size_t)cs*B_ + b)*N_ + col] = s;
}
__global__ __launch_bounds__(256) void ksqcomb(const float* __restrict__ part,
                                               float* __restrict__ out)
{
  int i = blockIdx.x*256 + threadIdx.x;   /* over B*N */
  float s = 0.f;
  for (int cs = 0; cs < CS_; ++cs) s += part[(size_t)cs*B_*N_ + i];
  out[i] = s;
}

/* ---- GEMM+exp: E = exp(2*A^T B - xx - yy), 128x128 tile, 8x8/thread ---- */
__global__ __launch_bounds__(256) void kgemm_exp(
    const float* __restrict__ Aemb, const float* __restrict__ Bemb,
    const float* __restrict__ xx, const float* __restrict__ yy,
    float* __restrict__ E, int b_off)
{
  int bn = blockIdx.x, bm = blockIdx.y, bz = blockIdx.z;
  int b = b_off + bz;
  const float* Ab = Aemb + (size_t)b*C_*N_ + bn*128;
  const float* Bb = Bemb + (size_t)b*C_*M_ + bm*128;
  __shared__ float As[16][128];
  __shared__ float Bs[16][128];
  int t = threadIdx.x;
  int tx = t & 15, ty = t >> 4;
  int lk = t >> 4;            /* staging row (k) */
  int ln = (t & 15) * 8;      /* staging col */
  float acc[8][8];
#pragma unroll
  for (int i = 0; i < 8; ++i)
#pragma unroll
    for (int j = 0; j < 8; ++j) acc[i][j] = 0.f;
  for (int k0 = 0; k0 < C_; k0 += 16) {
    const float* ag = Ab + (size_t)(k0+lk)*N_ + ln;
    const float* bg = Bb + (size_t)(k0+lk)*M_ + ln;
    float4 a0 = *(const float4*)ag, a1 = *(const float4*)(ag+4);
    float4 b0 = *(const float4*)bg, b1 = *(const float4*)(bg+4);
    __syncthreads();
    *(float4*)&As[lk][ln] = a0; *(float4*)&As[lk][ln+4] = a1;
    *(float4*)&Bs[lk][ln] = b0; *(float4*)&Bs[lk][ln+4] = b1;
    __syncthreads();
#pragma unroll
    for (int kk = 0; kk < 16; ++kk) {
      float av[8], bv[8];
      *(float4*)av     = *(const float4*)&As[kk][ty*8];
      *(float4*)(av+4) = *(const float4*)&As[kk][ty*8+4];
      *(float4*)bv     = *(const float4*)&Bs[kk][tx*8];
      *(float4*)(bv+4) = *(const float4*)&Bs[kk][tx*8+4];
#pragma unroll
      for (int i = 0; i < 8; ++i)
#pragma unroll
        for (int j = 0; j < 8; ++j) acc[i][j] += av[i]*bv[j];
    }
  }
  int n0 = bn*128 + ty*8, m0 = bm*128 + tx*8;
  float xv[8], yv[8];
#pragma unroll
  for (int i = 0; i < 8; ++i) xv[i] = xx[b*N_ + n0 + i];
#pragma unroll
  for (int j = 0; j < 8; ++j) yv[j] = yy[b*M_ + m0 + j];
  float* Eb = E + (size_t)bz*N_*M_;
#pragma unroll
  for (int i = 0; i < 8; ++i) {
    float o[8];
#pragma unroll
    for (int j = 0; j < 8; ++j) o[j] = expf(2.f*acc[i][j] - xv[i] - yv[j]);
    *(float4*)(Eb + (size_t)(n0+i)*M_ + m0)     = *(float4*)o;
    *(float4*)(Eb + (size_t)(n0+i)*M_ + m0 + 4) = *(float4*)(o+4);
  }
}

/* ---- per-row: rowZ = sum E (f64), rowSmax = maxE/rowZ ---- */
__global__ __launch_bounds__(256) void krowstat2(const float* __restrict__ E,
                                                 float* __restrict__ rowZf,
                                                 float* __restrict__ rowSmax, int b_off)
{
  __shared__ double shd[256];
  __shared__ float shf[256];
  int r = blockIdx.x, t = threadIdx.x;
  int bz = r / N_, n = r % N_;
  const float* row = E + (size_t)bz*N_*M_ + (size_t)n*M_;
  double s = 0.0; float mx = 0.f;
  for (int m = t*4; m < M_; m += 1024) {
    float4 v = *(const float4*)(row + m);
    s += (double)v.x + (double)v.y + (double)v.z + (double)v.w;
    mx = fmaxf(mx, fmaxf(fmaxf(v.x, v.y), fmaxf(v.z, v.w)));
  }
  s = blk_sumd(s, shd);
  mx = blk_max(mx, shf);
  if (!t) {
    int b = b_off + bz;
    float zf = (float)s;
    rowZf[b*N_+n] = zf;
    rowSmax[b*N_+n] = mx / zf;
  }
}

/* ---- column partials: colZ0 = sum_n E, colS = sum_n E/rowZ (f64) ---- */
__global__ __launch_bounds__(256) void kcolpart(const float* __restrict__ E,
                                                const float* __restrict__ rowZf,
                                                double* __restrict__ zpart,
                                                double* __restrict__ spart, int b_off)
{
  __shared__ double shz[256], shs[256];
  int t = threadIdx.x;
  int cx = t & 63, ry = t >> 6;
  int m = blockIdx.x*64 + cx;
  int rs = blockIdx.y, bz = blockIdx.z;
  int b = b_off + bz;
  const float* base = E + (size_t)bz*N_*M_;
  const float* rz = rowZf + b*N_ + rs*(N_/RS_);
  double z = 0.0, sp = 0.0;
  for (int rr = ry*32; rr < ry*32 + 32; ++rr) {
    int n = rs*(N_/RS_) + rr;
    float e = base[(size_t)n*M_ + m];
    z += (double)e;
    sp += (double)(e / rz[rr]);
  }
  shz[t] = z; shs[t] = sp; __syncthreads();
  if (ry == 0) {
    double zt = shz[cx] + shz[cx+64] + shz[cx+128] + shz[cx+192];
    double st = shs[cx] + shs[cx+64] + shs[cx+128] + shs[cx+192];
    size_t idx = ((size_t)rs*B_ + b)*M_ + m;
    zpart[idx] = zt; spart[idx] = st;
  }
}

__global__ __launch_bounds__(256) void kcolcomb(const double* __restrict__ zpart,
                                                const double* __restrict__ spart,
                                                float* __restrict__ colZ0f,
                                                double* __restrict__ col_sum,
                                                int b_off, int cur)
{
  int i = blockIdx.x*256 + threadIdx.x;   /* over cur*M */
  if (i >= cur*M_) return;
  int b = b_off + i/M_, m = i % M_;
  double z = 0.0, s = 0.0;
  for (int rs = 0; rs < RS_; ++rs) {
    size_t idx = ((size_t)rs*B_ + b)*M_ + m;
    z += zpart[idx]; s += spart[idx];
  }
  colZ0f[b*M_+m] = (float)z;
  col_sum[b*M_+m] = s;
}

/* ---- row_sum = sum_m E/colZ0 (f64, block per row) ---- */
__global__ __launch_bounds__(256) void krowsum2(const float* __restrict__ E,
                                                const float* __restrict__ colZ0f,
                                                double* __restrict__ row_sum, int b_off)
{
  __shared__ double shd[256];
  int r = blockIdx.x, t = threadIdx.x;
  int bz = r / N_, n = r % N_;
  int b = b_off + bz;
  const float* row = E + (size_t)bz*N_*M_ + (size_t)n*M_;
  const float* cz = colZ0f + b*M_;
  double s = 0.0;
  for (int m = t; m < M_; m += 256) s += (double)(row[m] / cz[m]);
  s = blk_sumd(s, shd);
  if (!t) row_sum[b*N_+n] = s;
}

/* ---- exact K-th smallest via rank count (parallel over candidates) ---- */
__global__ __launch_bounds__(256) void kkth(const double* __restrict__ vals,
                                            double* __restrict__ kth, int b_off)
{
  __shared__ double sv[2048];
  int b = b_off + blockIdx.y;
  const double* v = vals + b*2048;
  int t = threadIdx.x;
  for (int i = t; i < 2048; i += 256) sv[i] = v[i];
  __syncthreads();
  int i = blockIdx.x*256 + t;
  double vi = sv[i];
  int lt = 0, le = 0;
  for (int j = 0; j < 2048; ++j) { double vj = sv[j]; lt += (vj < vi); le += (vj <= vi); }
  if (lt < KSEL && KSEL <= le) kth[b] = vi;
}

/* ---- masks (float 0/1 outputs) ---- */
__global__ __launch_bounds__(256) void kmask(const double* __restrict__ vals,
                                             const double* __restrict__ kth,
                                             unsigned char* __restrict__ m8,
                                             float* __restrict__ mout,
                                             int b_off, int cur)
{
  int i = blockIdx.x*256 + threadIdx.x;
  if (i >= cur*2048) return;
  int b = b_off + i/2048, j = i & 2047;
  bool m = vals[b*2048 + j] < kth[b];
  m8[b*2048 + j] = m ? 1 : 0;
  mout[b*2048 + j] = m ? 1.f : 0.f;
}

/* ---- sparse renorm + vsi + src_corr (block per row) ---- */
__global__ __launch_bounds__(256) void kwcorr(
    const float* __restrict__ E, const float* __restrict__ rowZf,
    const float* __restrict__ rowSmax,
    const unsigned char* __restrict__ rowmask, const unsigned char* __restrict__ colmask,
    const float* __restrict__ tgt, float* __restrict__ vsi,
    float* __restrict__ corrf, float* __restrict__ corr_out, int b_off)
{
  __shared__ float rowc[M_];
  __shared__ float shf[256];
  int r = blockIdx.x, t = threadIdx.x;
  int bz = r / N_, n = r % N_;
  int b = b_off + bz;
  const float* row = E + (size_t)bz*N_*M_ + (size_t)n*M_;
  float zf = rowZf[b*N_+n];
  for (int m = t; m < M_; m += 256) rowc[m] = row[m] / zf;
  __syncthreads();
  float rmax = rowSmax[b*N_+n];
  int rm = rowmask[b*N_+n];
  const unsigned char* cm = colmask + b*M_;
  float s = 0.f;
  for (int m = t; m < M_; m += 256) {
    float v = rowc[m];
    if (rm || cm[m] || (v >= rmax)) s += v;
  }
  s = blk_sum(s, shf);
  float d = (s < EPS_) ? EPS_ : s;
  const float* t0 = tgt + (size_t)b*3*M_;
  float vs = 0.f, a0 = 0.f, a1 = 0.f, a2 = 0.f;
  for (int m = t; m < M_; m += 256) {
    float v = rowc[m];
    bool keep = rm || cm[m] || (v >= rmax);
    float wv = keep ? v/d : 0.f;
    vs += wv;
    a0 += wv * t0[m];
    a1 += wv * t0[M_+m];
    a2 += wv * t0[2*M_+m];
  }
  vs = blk_sum(vs, shf);
  a0 = blk_sum(a0, shf); a1 = blk_sum(a1, shf); a2 = blk_sum(a2, shf);
  if (!t) {
    vsi[b*N_+n] = rm ? 0.f : vs;
    size_t o = (size_t)b*3*N_ + n;
    corrf[o] = a0; corrf[o+N_] = a1; corrf[o+2*N_] = a2;
    corr_out[o]      = a0;
    corr_out[o+N_]   = a1;
    corr_out[o+2*N_] = a2;
  }
}

__global__ __launch_bounds__(256) void ksumvsi(const float* __restrict__ vsi,
                                               float* __restrict__ out)
{
  __shared__ double shd[256];
  int b = blockIdx.x;
  double s = 0.0;
  for (int n = threadIdx.x; n < N_; n += 256) s += (double)vsi[b*N_+n];
  s = blk_sumd(s, shd);
  if (!threadIdx.x) out[b] = (float)s;
}

__global__ __launch_bounds__(256) void kweights(const float* __restrict__ vsi,
                                                const float* __restrict__ sumvsi,
                                                float* __restrict__ srcw,
                                                float* __restrict__ wout)
{
  int i = blockIdx.x*256 + threadIdx.x;
  if (i >= B_*N_) return;
  int b = i / N_;
  float w = vsi[i] / sumvsi[b];
  srcw[i] = w;
  wout[i] = w;
}

__global__ __launch_bounds__(256) void kcov(const float* __restrict__ srcw,
                                            const float* __restrict__ src,
                                            const float* __restrict__ corrf,
                                            double* covd, double* cad, double* cbd)
{
  __shared__ double sh[256];
  int b = blockIdx.x, t = threadIdx.x;
  const float* w = srcw + b*N_;
  const float* a = src  + (size_t)b*3*N_;
  const float* bb = corrf + (size_t)b*3*N_;
  double sw = 0.0;
  for (int n = t; n < N_; n += 256) sw += (double)w[n];
  sw = blk_sumd(sw, sh);
  double inv = 1.0/(sw + 1e-5);
  double p0=0,p1=0,p2=0,p3=0,p4=0,p5=0;
  for (int n = t; n < N_; n += 256) {
    double wn = (double)w[n]*inv;
    p0 += (double)a[n]*wn;      p1 += (double)a[N_+n]*wn;   p2 += (double)a[2*N_+n]*wn;
    p3 += (double)bb[n]*wn;     p4 += (double)bb[N_+n]*wn;  p5 += (double)bb[2*N_+n]*wn;
  }
  double ca0 = blk_sumd(p0, sh), ca1 = blk_sumd(p1, sh), ca2 = blk_sumd(p2, sh);
  double cb0 = blk_sumd(p3, sh), cb1 = blk_sumd(p4, sh), cb2 = blk_sumd(p5, sh);
  double c[9] = {0,0,0,0,0,0,0,0,0};
  for (int n = t; n < N_; n += 256) {
    double wn = (double)w[n]*inv;
    double a0 = (double)a[n]-ca0, a1d = (double)a[N_+n]-ca1, a2d = (double)a[2*N_+n]-ca2;
    double b0 = ((double)bb[n]-cb0)*wn, b1 = ((double)bb[N_+n]-cb1)*wn, b2 = ((double)bb[2*N_+n]-cb2)*wn;
    c[0]+=a0*b0; c[1]+=a0*b1; c[2]+=a0*b2;
    c[3]+=a1d*b0; c[4]+=a1d*b1; c[5]+=a1d*b2;
    c[6]+=a2d*b0; c[7]+=a2d*b1; c[8]+=a2d*b2;
  }
  for (int k = 0; k < 9; ++k) {
    double rr = blk_sumd(c[k], sh);
    if (!t) covd[b*9+k] = rr;
  }
  if (!t) {
    cad[b*3+0]=ca0; cad[b*3+1]=ca1; cad[b*3+2]=ca2;
    cbd[b*3+0]=cb0; cbd[b*3+1]=cb1; cbd[b*3+2]=cb2;
  }
}

/* ---- 3x3 Kabsch via Jacobi eigendecomposition of H^T H (f64) ---- */
__global__ void ksvd(const double* __restrict__ covd, const double* __restrict__ cad,
                     const double* __restrict__ cbd, float* out)
{
  int b = threadIdx.x;
  if (b >= B_) return;
  double H[3][3];
  for (int i = 0; i < 3; ++i) for (int j = 0; j < 3; ++j) H[i][j] = covd[b*9+i*3+j];
  double A[3][3];
  for (int i = 0; i < 3; ++i)
    for (int j = 0; j < 3; ++j) {
      double s = 0.0;
      for (int l = 0; l < 3; ++l) s += H[l][i]*H[l][j];
      A[i][j] = s;
    }
  double V[3][3] = {{1,0,0},{0,1,0},{0,0,1}};
  const int PP[3] = {0,0,1}, QQ[3] = {1,2,2};
  for (int sweep = 0; sweep < 24; ++sweep) {
    double off = fabs(A[0][1])+fabs(A[0][2])+fabs(A[1][2]);
    if (off < 1e-28) break;
    for (int r = 0; r < 3; ++r) {
      int p = PP[r], q = QQ[r];
      double apq = A[p][q];
      if (fabs(apq) < 1e-300) continue;
      double th = (A[q][q]-A[p][p])/(2.0*apq);
      double tt = (th >= 0.0 ? 1.0 : -1.0)/(fabs(th)+sqrt(th*th+1.0));
      double cc = 1.0/sqrt(tt*tt+1.0), ss = tt*cc;
      for (int k = 0; k < 3; ++k) {
        double akp = A[k][p], akq = A[k][q];
        A[k][p] = cc*akp - ss*akq; A[k][q] = ss*akp + cc*akq;
      }
      for (int k = 0; k < 3; ++k) {
        double apk = A[p][k], aqk = A[q][k];
        A[p][k] = cc*apk - ss*aqk; A[q][k] = ss*apk + cc*aqk;
      }
      for (int k = 0; k < 3; ++k) {
        double vkp = V[k][p], vkq = V[k][q];
        V[k][p] = cc*vkp - ss*vkq; V[k][q] = ss*vkp + cc*vkq;
      }
    }
  }
  double lam[3] = {A[0][0], A[1][1], A[2][2]};
  int idx[3] = {0,1,2};
  for (int i = 0; i < 2; ++i)
    for (int j = i+1; j < 3; ++j)
      if (lam[idx[j]] > lam[idx[i]]) { int tmp = idx[i]; idx[i] = idx[j]; idx[j] = tmp; }
  double Vs[3][3], sig[3];
  for (int i = 0; i < 3; ++i) {
    for (int k = 0; k < 3; ++k) Vs[k][i] = V[k][idx[i]];
    double l = lam[idx[i]];
    sig[i] = sqrt(l > 0.0 ? l : 0.0);
  }
  double U[3][3];
  for (int i = 0; i < 3; ++i) {
    double inv = sig[i] > 1e-300 ? 1.0/sig[i] : 0.0;
    for (int k = 0; k < 3; ++k) {
      double u = H[k][0]*Vs[0][i] + H[k][1]*Vs[1][i] + H[k][2]*Vs[2][i];
      U[k][i] = u*inv;
    }
  }
  if (sig[2] <= 1e-9*sig[0]) {
    U[0][2] = U[1][0]*U[2][1] - U[2][0]*U[1][1];
    U[1][2] = U[2][0]*U[0][1] - U[0][0]*U[2][1];
    U[2][2] = U[0][0]*U[1][1] - U[1][0]*U[0][1];
  }
  double detH = H[0][0]*(H[1][1]*H[2][2]-H[1][2]*H[2][1])
              - H[0][1]*(H[1][0]*H[2][2]-H[1][2]*H[2][0])
              + H[0][2]*(H[1][0]*H[2][1]-H[1][1]*H[2][0]);
  double s3[3] = {1.0, 1.0, detH > 0.0 ? 1.0 : -1.0};
  double R[3][3];
  for (int d = 0; d < 3; ++d)
    for (int e = 0; e < 3; ++e) {
      double s = 0.0;
      for (int i = 0; i < 3; ++i) s += s3[i]*Vs[d][i]*U[e][i];
      R[d][e] = s;
    }
  double tr[3];
  for (int d = 0; d < 3; ++d)
    tr[d] = cbd[b*3+d] - (R[d][0]*cad[b*3+0] + R[d][1]*cad[b*3+1] + R[d][2]*cad[b*3+2]);
  for (int d = 0; d < 3; ++d)
    for (int e = 0; e < 3; ++e)
      out[O_ROT + b*9 + d*3 + e] = (float)R[d][e];
  for (int d = 0; d < 3; ++d)
    out[O_TR + b*3 + d] = (float)tr[d];
}

__global__ void kfail(float* out, float v) { out[0] = v; }

extern "C" void kernel_launch(void* const* d_in, const int* in_sizes, int n_in,
                              void* d_out, int out_size, void* d_ws, size_t ws_size,
                              hipStream_t stream) {
  float* out = (float*)d_out;
  (void)out_size;

  /* input-order auto-detect: dict (src,tgt,src_emb,tgt_emb) vs alphabetical */
  int i_tgt = 1, i_semb = 2;
  if (n_in == 4 && in_sizes[1] == B_*C_*N_) { i_semb = 1; i_tgt = 2; }
  const float* src  = (const float*)d_in[0];
  const float* tgt  = (const float*)d_in[i_tgt];
  const float* semb = (const float*)d_in[i_semb];
  const float* temb = (const float*)d_in[3];

  char* w = (char*)d_ws;
  auto alloc = [&](size_t bytes) { char* p = w; w += (bytes + 255)/256*256; return p; };
  float*  sqpart  = (float*)alloc((size_t)CS_*B_*N_*4);     /* 512KB, reused */
  float*  xx      = (float*)alloc((size_t)B_*N_*4);
  float*  yy      = (float*)alloc((size_t)B_*M_*4);
  float*  rowZf   = (float*)alloc((size_t)B_*N_*4);
  float*  rowSmax = (float*)alloc((size_t)B_*N_*4);
  float*  colZ0f  = (float*)alloc((size_t)B_*M_*4);
  double* zpart   = (double*)alloc((size_t)RS_*B_*M_*8);    /* 2MB */
  double* spart   = (double*)alloc((size_t)RS_*B_*M_*8);    /* 2MB */
  double* col_sum = (double*)alloc((size_t)B_*M_*8);
  double* row_sum = (double*)alloc((size_t)B_*N_*8);
  double* kth_c   = (double*)alloc((size_t)B_*8);
  double* kth_r   = (double*)alloc((size_t)B_*8);
  unsigned char* rowmask = (unsigned char*)alloc((size_t)B_*N_);
  unsigned char* colmask = (unsigned char*)alloc((size_t)B_*M_);
  float*  vsi     = (float*)alloc((size_t)B_*N_*4);
  float*  srcw    = (float*)alloc((size_t)B_*N_*4);
  float*  sumvsi  = (float*)alloc((size_t)B_*4);
  float*  corrf   = (float*)alloc((size_t)B_*3*N_*4);
  double* covd = (double*)alloc((size_t)B_*9*8);
  double* cad  = (double*)alloc((size_t)B_*3*8);
  double* cbd  = (double*)alloc((size_t)B_*3*8);

  size_t used = (size_t)(w - (char*)d_ws);
  size_t rem = ws_size > used ? ws_size - used : 0;
  size_t oneE = (size_t)N_*M_*sizeof(float);
  int bc = (int)(rem / oneE);
  if (bc < 1) { kfail<<<1, 1, 0, stream>>>(out, 32768.f); return; }
  if (bc > B_) bc = B_;
  float* E = (float*)w;

  /* xx / yy */
  ksqpart<<<dim3(N_/256, CS_, B_), 256, 0, stream>>>(semb, sqpart);
  ksqcomb<<<(B_*N_)/256, 256, 0, stream>>>(sqpart, xx);
  ksqpart<<<dim3(M_/256, CS_, B_), 256, 0, stream>>>(temb, sqpart);
  ksqcomb<<<(B_*M_)/256, 256, 0, stream>>>(sqpart, yy);

  for (int b0 = 0; b0 < B_; b0 += bc) {
    int cur = (B_ - b0 < bc) ? (B_ - b0) : bc;
    kgemm_exp<<<dim3(N_/128, M_/128, cur), 256, 0, stream>>>(semb, temb, xx, yy, E, b0);
    krowstat2<<<cur*N_, 256, 0, stream>>>(E, rowZf, rowSmax, b0);
    kcolpart <<<dim3(M_/64, RS_, cur), 256, 0, stream>>>(E, rowZf, zpart, spart, b0);
    kcolcomb <<<(cur*M_+255)/256, 256, 0, stream>>>(zpart, spart, colZ0f, col_sum, b0, cur);
    krowsum2 <<<cur*N_, 256, 0, stream>>>(E, colZ0f, row_sum, b0);
    kkth<<<dim3(8, cur), 256, 0, stream>>>(col_sum, kth_c, b0);
    kkth<<<dim3(8, cur), 256, 0, stream>>>(row_sum, kth_r, b0);
    kmask<<<cur*8, 256, 0, stream>>>(col_sum, kth_c, colmask, out + O_MTGT, b0, cur);
    kmask<<<cur*8, 256, 0, stream>>>(row_sum, kth_r, rowmask, out + O_MSRC, b0, cur);
    kwcorr<<<cur*N_, 256, 0, stream>>>(E, rowZf, rowSmax, rowmask, colmask, tgt,
                                       vsi, corrf, out + O_CORR, b0);
  }

  ksumvsi <<<B_, 256, 0, stream>>>(vsi, sumvsi);
  kweights<<<(B_*N_+255)/256, 256, 0, stream>>>(vsi, sumvsi, srcw, out + O_W);
  kcov    <<<B_, 256, 0, stream>>>(srcw, src, corrf, covd, cad, cbd);
  ksvd    <<<1, 64, 0, stream>>>(covd, cad, cbd, out);
}

// Round 7
// 704.207 us; speedup vs baseline: 4.2130x; 1.0062x over previous
//
#include <hip/hip_runtime.h>
#include <math.h>

#define B_ 8
#define C_ 512
#define N_ 2048
#define M_ 2048
#define KSEL 614          /* int(2048*0.3) */
#define EPS_ 1e-5f
#define CS_ 8             /* c-chunks for ksq partials */
#define RS_ 16            /* row-chunks for column partials */

#define O_CORR 0
#define O_W    (B_*3*N_)          /* 49152 */
#define O_MSRC (O_W + B_*N_)      /* 65536 */
#define O_MTGT (O_MSRC + B_*N_)   /* 81920 */
#define O_ROT  (O_MTGT + B_*M_)   /* 98304 */
#define O_TR   (O_ROT + B_*9)     /* 98376 */

typedef short bf16x8 __attribute__((ext_vector_type(8)));
typedef float f32x4 __attribute__((ext_vector_type(4)));

__device__ inline unsigned short f2bf(float f){
  unsigned u = __float_as_uint(f);
  return (unsigned short)((u + 0x7FFFu + ((u >> 16) & 1u)) >> 16);
}
__device__ inline float bf2f(unsigned short h){
  return __uint_as_float(((unsigned)h) << 16);
}

/* ---- fixed-order block tree reductions (256 threads) ---- */
__device__ inline float blk_sum(float v, float* sh){
  int t = threadIdx.x;
  sh[t] = v; __syncthreads();
  for (int s = 128; s > 0; s >>= 1) { if (t < s) sh[t] += sh[t+s]; __syncthreads(); }
  float r = sh[0]; __syncthreads(); return r;
}
__device__ inline float blk_max(float v, float* sh){
  int t = threadIdx.x;
  sh[t] = v; __syncthreads();
  for (int s = 128; s > 0; s >>= 1) { if (t < s) sh[t] = fmaxf(sh[t], sh[t+s]); __syncthreads(); }
  float r = sh[0]; __syncthreads(); return r;
}
__device__ inline double blk_sumd(double v, double* sh){
  int t = threadIdx.x;
  sh[t] = v; __syncthreads();
  for (int s = 128; s > 0; s >>= 1) { if (t < s) sh[t] += sh[t+s]; __syncthreads(); }
  double r = sh[0]; __syncthreads(); return r;
}

/* ---- xx/yy sum-of-squares: two-stage ---- */
__global__ __launch_bounds__(256) void ksqpart(const float* __restrict__ X,
                                               float* __restrict__ part)
{
  int col = blockIdx.x*256 + threadIdx.x;
  int cs = blockIdx.y, b = blockIdx.z;
  const float* base = X + (size_t)b*C_*N_;
  float s = 0.f;
  for (int c = cs*(C_/CS_); c < (cs+1)*(C_/CS_); ++c) {
    float v = base[(size_t)c*N_ + col]; s += v*v;
  }
  part[((size_t)cs*B_ + b)*N_ + col] = s;
}
__global__ __launch_bounds__(256) void ksqcomb(const float* __restrict__ part,
                                               float* __restrict__ out)
{
  int i = blockIdx.x*256 + threadIdx.x;
  float s = 0.f;
  for (int cs = 0; cs < CS_; ++cs) s += part[(size_t)cs*B_*N_ + i];
  out[i] = s;
}

/* ---- split f32 [B][C][P] -> hi/lo bf16 [B][P][C] (transpose via LDS) ---- */
__global__ __launch_bounds__(256) void ksplit(const float* __restrict__ X,
                                              unsigned short* __restrict__ Xh,
                                              unsigned short* __restrict__ Xl)
{
  __shared__ float tile[64][65];  /* [p][c] */
  int p0 = blockIdx.x*64, c0 = blockIdx.y*64, b = blockIdx.z;
  int t = threadIdx.x;
  const float* base = X + ((size_t)b*C_ + c0)*N_ + p0;
  int px = (t & 15)*4, cy = t >> 4;
#pragma unroll
  for (int i = 0; i < 4; ++i) {
    int c = cy + i*16;
    float4 v = *(const float4*)(base + (size_t)c*N_ + px);
    tile[px+0][c] = v.x; tile[px+1][c] = v.y; tile[px+2][c] = v.z; tile[px+3][c] = v.w;
  }
  __syncthreads();
  int cx = (t & 15)*4, py = t >> 4;
  unsigned short* oh = Xh + ((size_t)b*N_ + p0)*C_ + c0;
  unsigned short* ol = Xl + ((size_t)b*N_ + p0)*C_ + c0;
#pragma unroll
  for (int i = 0; i < 4; ++i) {
    int p = py + i*16;
    float v0 = tile[p][cx], v1 = tile[p][cx+1], v2 = tile[p][cx+2], v3 = tile[p][cx+3];
    ushort4 h, l;
    h.x = f2bf(v0); l.x = f2bf(v0 - bf2f(h.x));
    h.y = f2bf(v1); l.y = f2bf(v1 - bf2f(h.y));
    h.z = f2bf(v2); l.z = f2bf(v2 - bf2f(h.z));
    h.w = f2bf(v3); l.w = f2bf(v3 - bf2f(h.w));
    *(ushort4*)(oh + (size_t)p*C_ + cx) = h;
    *(ushort4*)(ol + (size_t)p*C_ + cx) = l;
  }
}

/* ---- MFMA GEMM: E = exp(2*(Ah+Al)^T(Bh+Bl) - xx - yy), 3-term split-bf16 ---- */
__global__ __launch_bounds__(256) void kgemm_mfma(
    const unsigned short* __restrict__ Ahg, const unsigned short* __restrict__ Alg,
    const unsigned short* __restrict__ Bhg, const unsigned short* __restrict__ Blg,
    const float* __restrict__ xx, const float* __restrict__ yy,
    float* __restrict__ E, int b_off)
{
  /* LDS rows padded to 40 ushorts (80B) -> 2-way (free) bank pattern */
  __shared__ unsigned short Ahs[128*40], Als[128*40], Bhs[128*40], Bls[128*40];
  int bn = blockIdx.x, bm = blockIdx.y, bz = blockIdx.z;
  int b = b_off + bz;
  int t = threadIdx.x;
  size_t abase = ((size_t)b*N_ + (size_t)bn*128)*C_;
  size_t bbase = ((size_t)b*M_ + (size_t)bm*128)*C_;
  int g0 = t, g1 = t + 256;
  int r0 = g0 >> 2, c0g = (g0 & 3)*8;
  int r1 = g1 >> 2, c1g = (g1 & 3)*8;

  f32x4 acc[4][4];
#pragma unroll
  for (int i = 0; i < 4; ++i)
#pragma unroll
    for (int j = 0; j < 4; ++j) acc[i][j] = (f32x4){0.f, 0.f, 0.f, 0.f};

  uint4 pre[8];
#define LOADS(K0) do { \
    pre[0] = *(const uint4*)(Ahg + abase + (size_t)r0*C_ + (K0) + c0g); \
    pre[1] = *(const uint4*)(Ahg + abase + (size_t)r1*C_ + (K0) + c1g); \
    pre[2] = *(const uint4*)(Alg + abase + (size_t)r0*C_ + (K0) + c0g); \
    pre[3] = *(const uint4*)(Alg + abase + (size_t)r1*C_ + (K0) + c1g); \
    pre[4] = *(const uint4*)(Bhg + bbase + (size_t)r0*C_ + (K0) + c0g); \
    pre[5] = *(const uint4*)(Bhg + bbase + (size_t)r1*C_ + (K0) + c1g); \
    pre[6] = *(const uint4*)(Blg + bbase + (size_t)r0*C_ + (K0) + c0g); \
    pre[7] = *(const uint4*)(Blg + bbase + (size_t)r1*C_ + (K0) + c1g); \
  } while (0)

  int lane = t & 63, w = t >> 6;
  int wr = (w >> 1)*64, wc = (w & 1)*64;
  int lrow = lane & 15, lgr = (lane >> 4)*8;

  LOADS(0);
  for (int ks = 0; ks < 16; ++ks) {
    __syncthreads();
    *(uint4*)&Ahs[r0*40 + c0g] = pre[0];
    *(uint4*)&Ahs[r1*40 + c1g] = pre[1];
    *(uint4*)&Als[r0*40 + c0g] = pre[2];
    *(uint4*)&Als[r1*40 + c1g] = pre[3];
    *(uint4*)&Bhs[r0*40 + c0g] = pre[4];
    *(uint4*)&Bhs[r1*40 + c1g] = pre[5];
    *(uint4*)&Bls[r0*40 + c0g] = pre[6];
    *(uint4*)&Bls[r1*40 + c1g] = pre[7];
    __syncthreads();
    if (ks < 15) { int k0n = (ks+1)*32; LOADS(k0n); }
    bf16x8 ah[4], al[4], bh[4], bl[4];
#pragma unroll
    for (int f = 0; f < 4; ++f) {
      int ra = (wr + f*16 + lrow)*40 + lgr;
      int rb = (wc + f*16 + lrow)*40 + lgr;
      ah[f] = *(const bf16x8*)&Ahs[ra];
      al[f] = *(const bf16x8*)&Als[ra];
      bh[f] = *(const bf16x8*)&Bhs[rb];
      bl[f] = *(const bf16x8*)&Bls[rb];
    }
#pragma unroll
    for (int fi = 0; fi < 4; ++fi)
#pragma unroll
      for (int fj = 0; fj < 4; ++fj) {
        acc[fi][fj] = __builtin_amdgcn_mfma_f32_16x16x32_bf16(ah[fi], bh[fj], acc[fi][fj], 0, 0, 0);
        acc[fi][fj] = __builtin_amdgcn_mfma_f32_16x16x32_bf16(ah[fi], bl[fj], acc[fi][fj], 0, 0, 0);
        acc[fi][fj] = __builtin_amdgcn_mfma_f32_16x16x32_bf16(al[fi], bh[fj], acc[fi][fj], 0, 0, 0);
      }
  }
#undef LOADS
  /* epilogue: D[m=(l>>4)*4+r][n=l&15] with m->our n (A rows), n->our m (B cols) */
  float* Eb = E + (size_t)bz*N_*M_;
  int n_base = bn*128 + wr + (lane >> 4)*4;
  int m_base = bm*128 + wc + (lane & 15);
#pragma unroll
  for (int fi = 0; fi < 4; ++fi) {
    int nf = n_base + fi*16;
#pragma unroll
    for (int fj = 0; fj < 4; ++fj) {
      int mf = m_base + fj*16;
      float ym = yy[b*M_ + mf];
#pragma unroll
      for (int r = 0; r < 4; ++r) {
        float pv = 2.f*acc[fi][fj][r] - xx[b*N_ + nf + r] - ym;
        Eb[(size_t)(nf + r)*M_ + mf] = expf(pv);
      }
    }
  }
}

/* ---- per-row: rowZ = sum E (f64), rowSmax = maxE/rowZ ---- */
__global__ __launch_bounds__(256) void krowstat2(const float* __restrict__ E,
                                                 float* __restrict__ rowZf,
                                                 float* __restrict__ rowSmax, int b_off)
{
  __shared__ double shd[256];
  __shared__ float shf[256];
  int r = blockIdx.x, t = threadIdx.x;
  int bz = r / N_, n = r % N_;
  const float* row = E + (size_t)bz*N_*M_ + (size_t)n*M_;
  double s = 0.0; float mx = 0.f;
  for (int m = t*4; m < M_; m += 1024) {
    float4 v = *(const float4*)(row + m);
    s += (double)v.x + (double)v.y + (double)v.z + (double)v.w;
    mx = fmaxf(mx, fmaxf(fmaxf(v.x, v.y), fmaxf(v.z, v.w)));
  }
  s = blk_sumd(s, shd);
  mx = blk_max(mx, shf);
  if (!t) {
    int b = b_off + bz;
    float zf = (float)s;
    rowZf[b*N_+n] = zf;
    rowSmax[b*N_+n] = mx / zf;
  }
}

/* ---- column partials: colZ0 = sum_n E, colS = sum_n E/rowZ (f64) ---- */
__global__ __launch_bounds__(256) void kcolpart(const float* __restrict__ E,
                                                const float* __restrict__ rowZf,
                                                double* __restrict__ zpart,
                                                double* __restrict__ spart, int b_off)
{
  __shared__ double shz[256], shs[256];
  int t = threadIdx.x;
  int cx = t & 63, ry = t >> 6;
  int m = blockIdx.x*64 + cx;
  int rs = blockIdx.y, bz = blockIdx.z;
  int b = b_off + bz;
  const float* base = E + (size_t)bz*N_*M_;
  const float* rz = rowZf + b*N_ + rs*(N_/RS_);
  double z = 0.0, sp = 0.0;
  for (int rr = ry*32; rr < ry*32 + 32; ++rr) {
    int n = rs*(N_/RS_) + rr;
    float e = base[(size_t)n*M_ + m];
    z += (double)e;
    sp += (double)(e / rz[rr]);
  }
  shz[t] = z; shs[t] = sp; __syncthreads();
  if (ry == 0) {
    double zt = shz[cx] + shz[cx+64] + shz[cx+128] + shz[cx+192];
    double st = shs[cx] + shs[cx+64] + shs[cx+128] + shs[cx+192];
    size_t idx = ((size_t)rs*B_ + b)*M_ + m;
    zpart[idx] = zt; spart[idx] = st;
  }
}

__global__ __launch_bounds__(256) void kcolcomb(const double* __restrict__ zpart,
                                                const double* __restrict__ spart,
                                                float* __restrict__ colZ0f,
                                                double* __restrict__ col_sum,
                                                int b_off, int cur)
{
  int i = blockIdx.x*256 + threadIdx.x;
  if (i >= cur*M_) return;
  int b = b_off + i/M_, m = i % M_;
  double z = 0.0, s = 0.0;
  for (int rs = 0; rs < RS_; ++rs) {
    size_t idx = ((size_t)rs*B_ + b)*M_ + m;
    z += zpart[idx]; s += spart[idx];
  }
  colZ0f[b*M_+m] = (float)z;
  col_sum[b*M_+m] = s;
}

/* ---- row_sum = sum_m E/colZ0 (f64, block per row) ---- */
__global__ __launch_bounds__(256) void krowsum2(const float* __restrict__ E,
                                                const float* __restrict__ colZ0f,
                                                double* __restrict__ row_sum, int b_off)
{
  __shared__ double shd[256];
  int r = blockIdx.x, t = threadIdx.x;
  int bz = r / N_, n = r % N_;
  int b = b_off + bz;
  const float* row = E + (size_t)bz*N_*M_ + (size_t)n*M_;
  const float* cz = colZ0f + b*M_;
  double s = 0.0;
  for (int m = t; m < M_; m += 256) s += (double)(row[m] / cz[m]);
  s = blk_sumd(s, shd);
  if (!t) row_sum[b*N_+n] = s;
}

/* ---- exact K-th smallest via rank count (parallel over candidates) ---- */
__global__ __launch_bounds__(256) void kkth(const double* __restrict__ vals,
                                            double* __restrict__ kth, int b_off)
{
  __shared__ double sv[2048];
  int b = b_off + blockIdx.y;
  const double* v = vals + b*2048;
  int t = threadIdx.x;
  for (int i = t; i < 2048; i += 256) sv[i] = v[i];
  __syncthreads();
  int i = blockIdx.x*256 + t;
  double vi = sv[i];
  int lt = 0, le = 0;
  for (int j = 0; j < 2048; ++j) { double vj = sv[j]; lt += (vj < vi); le += (vj <= vi); }
  if (lt < KSEL && KSEL <= le) kth[b] = vi;
}

/* ---- masks (float 0/1 outputs) ---- */
__global__ __launch_bounds__(256) void kmask(const double* __restrict__ vals,
                                             const double* __restrict__ kth,
                                             unsigned char* __restrict__ m8,
                                             float* __restrict__ mout,
                                             int b_off, int cur)
{
  int i = blockIdx.x*256 + threadIdx.x;
  if (i >= cur*2048) return;
  int b = b_off + i/2048, j = i & 2047;
  bool m = vals[b*2048 + j] < kth[b];
  m8[b*2048 + j] = m ? 1 : 0;
  mout[b*2048 + j] = m ? 1.f : 0.f;
}

/* ---- sparse renorm + vsi + src_corr (block per row) ---- */
__global__ __launch_bounds__(256) void kwcorr(
    const float* __restrict__ E, const float* __restrict__ rowZf,
    const float* __restrict__ rowSmax,
    const unsigned char* __restrict__ rowmask, const unsigned char* __restrict__ colmask,
    const float* __restrict__ tgt, float* __restrict__ vsi,
    float* __restrict__ corrf, float* __restrict__ corr_out, int b_off)
{
  __shared__ float rowc[M_];
  __shared__ float shf[256];
  int r = blockIdx.x, t = threadIdx.x;
  int bz = r / N_, n = r % N_;
  int b = b_off + bz;
  const float* row = E + (size_t)bz*N_*M_ + (size_t)n*M_;
  float zf = rowZf[b*N_+n];
  for (int m = t; m < M_; m += 256) rowc[m] = row[m] / zf;
  __syncthreads();
  float rmax = rowSmax[b*N_+n];
  int rm = rowmask[b*N_+n];
  const unsigned char* cm = colmask + b*M_;
  float s = 0.f;
  for (int m = t; m < M_; m += 256) {
    float v = rowc[m];
    if (rm || cm[m] || (v >= rmax)) s += v;
  }
  s = blk_sum(s, shf);
  float d = (s < EPS_) ? EPS_ : s;
  const float* t0 = tgt + (size_t)b*3*M_;
  float vs = 0.f, a0 = 0.f, a1 = 0.f, a2 = 0.f;
  for (int m = t; m < M_; m += 256) {
    float v = rowc[m];
    bool keep = rm || cm[m] || (v >= rmax);
    float wv = keep ? v/d : 0.f;
    vs += wv;
    a0 += wv * t0[m];
    a1 += wv * t0[M_+m];
    a2 += wv * t0[2*M_+m];
  }
  vs = blk_sum(vs, shf);
  a0 = blk_sum(a0, shf); a1 = blk_sum(a1, shf); a2 = blk_sum(a2, shf);
  if (!t) {
    vsi[b*N_+n] = rm ? 0.f : vs;
    size_t o = (size_t)b*3*N_ + n;
    corrf[o] = a0; corrf[o+N_] = a1; corrf[o+2*N_] = a2;
    corr_out[o]      = a0;
    corr_out[o+N_]   = a1;
    corr_out[o+2*N_] = a2;
  }
}

__global__ __launch_bounds__(256) void ksumvsi(const float* __restrict__ vsi,
                                               float* __restrict__ out)
{
  __shared__ double shd[256];
  int b = blockIdx.x;
  double s = 0.0;
  for (int n = threadIdx.x; n < N_; n += 256) s += (double)vsi[b*N_+n];
  s = blk_sumd(s, shd);
  if (!threadIdx.x) out[b] = (float)s;
}

__global__ __launch_bounds__(256) void kweights(const float* __restrict__ vsi,
                                                const float* __restrict__ sumvsi,
                                                float* __restrict__ srcw,
                                                float* __restrict__ wout)
{
  int i = blockIdx.x*256 + threadIdx.x;
  if (i >= B_*N_) return;
  int b = i / N_;
  float w = vsi[i] / sumvsi[b];
  srcw[i] = w;
  wout[i] = w;
}

__global__ __launch_bounds__(256) void kcov(const float* __restrict__ srcw,
                                            const float* __restrict__ src,
                                            const float* __restrict__ corrf,
                                            double* covd, double* cad, double* cbd)
{
  __shared__ double sh[256];
  int b = blockIdx.x, t = threadIdx.x;
  const float* w = srcw + b*N_;
  const float* a = src  + (size_t)b*3*N_;
  const float* bb = corrf + (size_t)b*3*N_;
  double sw = 0.0;
  for (int n = t; n < N_; n += 256) sw += (double)w[n];
  sw = blk_sumd(sw, sh);
  double inv = 1.0/(sw + 1e-5);
  double p0=0,p1=0,p2=0,p3=0,p4=0,p5=0;
  for (int n = t; n < N_; n += 256) {
    double wn = (double)w[n]*inv;
    p0 += (double)a[n]*wn;      p1 += (double)a[N_+n]*wn;   p2 += (double)a[2*N_+n]*wn;
    p3 += (double)bb[n]*wn;     p4 += (double)bb[N_+n]*wn;  p5 += (double)bb[2*N_+n]*wn;
  }
  double ca0 = blk_sumd(p0, sh), ca1 = blk_sumd(p1, sh), ca2 = blk_sumd(p2, sh);
  double cb0 = blk_sumd(p3, sh), cb1 = blk_sumd(p4, sh), cb2 = blk_sumd(p5, sh);
  double c[9] = {0,0,0,0,0,0,0,0,0};
  for (int n = t; n < N_; n += 256) {
    double wn = (double)w[n]*inv;
    double a0 = (double)a[n]-ca0, a1d = (double)a[N_+n]-ca1, a2d = (double)a[2*N_+n]-ca2;
    double b0 = ((double)bb[n]-cb0)*wn, b1 = ((double)bb[N_+n]-cb1)*wn, b2 = ((double)bb[2*N_+n]-cb2)*wn;
    c[0]+=a0*b0; c[1]+=a0*b1; c[2]+=a0*b2;
    c[3]+=a1d*b0; c[4]+=a1d*b1; c[5]+=a1d*b2;
    c[6]+=a2d*b0; c[7]+=a2d*b1; c[8]+=a2d*b2;
  }
  for (int k = 0; k < 9; ++k) {
    double rr = blk_sumd(c[k], sh);
    if (!t) covd[b*9+k] = rr;
  }
  if (!t) {
    cad[b*3+0]=ca0; cad[b*3+1]=ca1; cad[b*3+2]=ca2;
    cbd[b*3+0]=cb0; cbd[b*3+1]=cb1; cbd[b*3+2]=cb2;
  }
}

/* ---- 3x3 Kabsch via Jacobi eigendecomposition of H^T H (f64) ---- */
__global__ void ksvd(const double* __restrict__ covd, const double* __restrict__ cad,
                     const double* __restrict__ cbd, float* out)
{
  int b = threadIdx.x;
  if (b >= B_) return;
  double H[3][3];
  for (int i = 0; i < 3; ++i) for (int j = 0; j < 3; ++j) H[i][j] = covd[b*9+i*3+j];
  double A[3][3];
  for (int i = 0; i < 3; ++i)
    for (int j = 0; j < 3; ++j) {
      double s = 0.0;
      for (int l = 0; l < 3; ++l) s += H[l][i]*H[l][j];
      A[i][j] = s;
    }
  double V[3][3] = {{1,0,0},{0,1,0},{0,0,1}};
  const int PP[3] = {0,0,1}, QQ[3] = {1,2,2};
  for (int sweep = 0; sweep < 24; ++sweep) {
    double off = fabs(A[0][1])+fabs(A[0][2])+fabs(A[1][2]);
    if (off < 1e-28) break;
    for (int r = 0; r < 3; ++r) {
      int p = PP[r], q = QQ[r];
      double apq = A[p][q];
      if (fabs(apq) < 1e-300) continue;
      double th = (A[q][q]-A[p][p])/(2.0*apq);
      double tt = (th >= 0.0 ? 1.0 : -1.0)/(fabs(th)+sqrt(th*th+1.0));
      double cc = 1.0/sqrt(tt*tt+1.0), ss = tt*cc;
      for (int k = 0; k < 3; ++k) {
        double akp = A[k][p], akq = A[k][q];
        A[k][p] = cc*akp - ss*akq; A[k][q] = ss*akp + cc*akq;
      }
      for (int k = 0; k < 3; ++k) {
        double apk = A[p][k], aqk = A[q][k];
        A[p][k] = cc*apk - ss*aqk; A[q][k] = ss*apk + cc*aqk;
      }
      for (int k = 0; k < 3; ++k) {
        double vkp = V[k][p], vkq = V[k][q];
        V[k][p] = cc*vkp - ss*vkq; V[k][q] = ss*vkp + cc*vkq;
      }
    }
  }
  double lam[3] = {A[0][0], A[1][1], A[2][2]};
  int idx[3] = {0,1,2};
  for (int i = 0; i < 2; ++i)
    for (int j = i+1; j < 3; ++j)
      if (lam[idx[j]] > lam[idx[i]]) { int tmp = idx[i]; idx[i] = idx[j]; idx[j] = tmp; }
  double Vs[3][3], sig[3];
  for (int i = 0; i < 3; ++i) {
    for (int k = 0; k < 3; ++k) Vs[k][i] = V[k][idx[i]];
    double l = lam[idx[i]];
    sig[i] = sqrt(l > 0.0 ? l : 0.0);
  }
  double U[3][3];
  for (int i = 0; i < 3; ++i) {
    double inv = sig[i] > 1e-300 ? 1.0/sig[i] : 0.0;
    for (int k = 0; k < 3; ++k) {
      double u = H[k][0]*Vs[0][i] + H[k][1]*Vs[1][i] + H[k][2]*Vs[2][i];
      U[k][i] = u*inv;
    }
  }
  if (sig[2] <= 1e-9*sig[0]) {
    U[0][2] = U[1][0]*U[2][1] - U[2][0]*U[1][1];
    U[1][2] = U[2][0]*U[0][1] - U[0][0]*U[2][1];
    U[2][2] = U[0][0]*U[1][1] - U[1][0]*U[0][1];
  }
  double detH = H[0][0]*(H[1][1]*H[2][2]-H[1][2]*H[2][1])
              - H[0][1]*(H[1][0]*H[2][2]-H[1][2]*H[2][0])
              + H[0][2]*(H[1][0]*H[2][1]-H[1][1]*H[2][0]);
  double s3[3] = {1.0, 1.0, detH > 0.0 ? 1.0 : -1.0};
  double R[3][3];
  for (int d = 0; d < 3; ++d)
    for (int e = 0; e < 3; ++e) {
      double s = 0.0;
      for (int i = 0; i < 3; ++i) s += s3[i]*Vs[d][i]*U[e][i];
      R[d][e] = s;
    }
  double tr[3];
  for (int d = 0; d < 3; ++d)
    tr[d] = cbd[b*3+d] - (R[d][0]*cad[b*3+0] + R[d][1]*cad[b*3+1] + R[d][2]*cad[b*3+2]);
  for (int d = 0; d < 3; ++d)
    for (int e = 0; e < 3; ++e)
      out[O_ROT + b*9 + d*3 + e] = (float)R[d][e];
  for (int d = 0; d < 3; ++d)
    out[O_TR + b*3 + d] = (float)tr[d];
}

__global__ void kfail(float* out, float v) { out[0] = v; }

extern "C" void kernel_launch(void* const* d_in, const int* in_sizes, int n_in,
                              void* d_out, int out_size, void* d_ws, size_t ws_size,
                              hipStream_t stream) {
  float* out = (float*)d_out;
  (void)out_size;

  /* input-order auto-detect: dict (src,tgt,src_emb,tgt_emb) vs alphabetical */
  int i_tgt = 1, i_semb = 2;
  if (n_in == 4 && in_sizes[1] == B_*C_*N_) { i_semb = 1; i_tgt = 2; }
  const float* src  = (const float*)d_in[0];
  const float* tgt  = (const float*)d_in[i_tgt];
  const float* semb = (const float*)d_in[i_semb];
  const float* temb = (const float*)d_in[3];

  char* w = (char*)d_ws;
  auto alloc = [&](size_t bytes) { char* p = w; w += (bytes + 255)/256*256; return p; };
  float*  sqpart  = (float*)alloc((size_t)CS_*B_*N_*4);
  float*  xx      = (float*)alloc((size_t)B_*N_*4);
  float*  yy      = (float*)alloc((size_t)B_*M_*4);
  float*  rowZf   = (float*)alloc((size_t)B_*N_*4);
  float*  rowSmax = (float*)alloc((size_t)B_*N_*4);
  float*  colZ0f  = (float*)alloc((size_t)B_*M_*4);
  double* zpart   = (double*)alloc((size_t)RS_*B_*M_*8);
  double* spart   = (double*)alloc((size_t)RS_*B_*M_*8);
  double* col_sum = (double*)alloc((size_t)B_*M_*8);
  double* row_sum = (double*)alloc((size_t)B_*N_*8);
  double* kth_c   = (double*)alloc((size_t)B_*8);
  double* kth_r   = (double*)alloc((size_t)B_*8);
  unsigned char* rowmask = (unsigned char*)alloc((size_t)B_*N_);
  unsigned char* colmask = (unsigned char*)alloc((size_t)B_*M_);
  float*  vsi     = (float*)alloc((size_t)B_*N_*4);
  float*  srcw    = (float*)alloc((size_t)B_*N_*4);
  float*  sumvsi  = (float*)alloc((size_t)B_*4);
  float*  corrf   = (float*)alloc((size_t)B_*3*N_*4);
  double* covd = (double*)alloc((size_t)B_*9*8);
  double* cad  = (double*)alloc((size_t)B_*3*8);
  double* cbd  = (double*)alloc((size_t)B_*3*8);
  /* split-bf16 operand arrays [B][pos][C] */
  unsigned short* Ahg = (unsigned short*)alloc((size_t)B_*N_*C_*2);
  unsigned short* Alg = (unsigned short*)alloc((size_t)B_*N_*C_*2);
  unsigned short* Bhg = (unsigned short*)alloc((size_t)B_*M_*C_*2);
  unsigned short* Blg = (unsigned short*)alloc((size_t)B_*M_*C_*2);

  size_t used = (size_t)(w - (char*)d_ws);
  size_t rem = ws_size > used ? ws_size - used : 0;
  size_t oneE = (size_t)N_*M_*sizeof(float);
  int bc = (int)(rem / oneE);
  if (bc < 1) { kfail<<<1, 1, 0, stream>>>(out, 32768.f); return; }
  if (bc > B_) bc = B_;
  float* E = (float*)w;

  /* xx / yy */
  ksqpart<<<dim3(N_/256, CS_, B_), 256, 0, stream>>>(semb, sqpart);
  ksqcomb<<<(B_*N_)/256, 256, 0, stream>>>(sqpart, xx);
  ksqpart<<<dim3(M_/256, CS_, B_), 256, 0, stream>>>(temb, sqpart);
  ksqcomb<<<(B_*M_)/256, 256, 0, stream>>>(sqpart, yy);

  /* split + transpose both embeddings */
  ksplit<<<dim3(N_/64, C_/64, B_), 256, 0, stream>>>(semb, Ahg, Alg);
  ksplit<<<dim3(M_/64, C_/64, B_), 256, 0, stream>>>(temb, Bhg, Blg);

  for (int b0 = 0; b0 < B_; b0 += bc) {
    int cur = (B_ - b0 < bc) ? (B_ - b0) : bc;
    kgemm_mfma<<<dim3(N_/128, M_/128, cur), 256, 0, stream>>>(Ahg, Alg, Bhg, Blg,
                                                              xx, yy, E, b0);
    krowstat2<<<cur*N_, 256, 0, stream>>>(E, rowZf, rowSmax, b0);
    kcolpart <<<dim3(M_/64, RS_, cur), 256, 0, stream>>>(E, rowZf, zpart, spart, b0);
    kcolcomb <<<(cur*M_+255)/256, 256, 0, stream>>>(zpart, spart, colZ0f, col_sum, b0, cur);
    krowsum2 <<<cur*N_, 256, 0, stream>>>(E, colZ0f, row_sum, b0);
    kkth<<<dim3(8, cur), 256, 0, stream>>>(col_sum, kth_c, b0);
    kkth<<<dim3(8, cur), 256, 0, stream>>>(row_sum, kth_r, b0);
    kmask<<<cur*8, 256, 0, stream>>>(col_sum, kth_c, colmask, out + O_MTGT, b0, cur);
    kmask<<<cur*8, 256, 0, stream>>>(row_sum, kth_r, rowmask, out + O_MSRC, b0, cur);
    kwcorr<<<cur*N_, 256, 0, stream>>>(E, rowZf, rowSmax, rowmask, colmask, tgt,
                                       vsi, corrf, out + O_CORR, b0);
  }

  ksumvsi <<<B_, 256, 0, stream>>>(vsi, sumvsi);
  kweights<<<(B_*N_+255)/256, 256, 0, stream>>>(vsi, sumvsi, srcw, out + O_W);
  kcov    <<<B_, 256, 0, stream>>>(srcw, src, corrf, covd, cad, cbd);
  ksvd    <<<1, 64, 0, stream>>>(covd, cad, cbd, out);
}